// Round 14
// baseline (16.713 us; speedup 1.0000x reference)
//
#include <hip/hip_runtime.h>
#include <hip/hip_fp16.h>

// ComplexMixture: B=32, S=128, N=256
// Or[b,n,m] = sum_s w[b,s]*(r[b,s,n]*r[b,s,m] + i[b,s,n]*i[b,s,m])
// Oi[b,n,m] = sum_s w[b,s]*(i[b,s,n]*r[b,s,m] - r[b,s,n]*i[b,s,m])
//
// R14 = R12 schedule (all 8 waves MFMA every phase, K-half pipeline,
// counted lgkm-only barriers) + R13-verified 32x32x16 MFMA. Block =
// 128n x 64m = 4x2 grid of 32x32 wave-tiles -> fragment traffic 256 b128/CU
// (R12: 384) with no wave idling (R13's mistake). Staging: every thread
// stages A (8 float4/half), u<128 also stage B -> peak ~160 VGPR (R11's
// 128-reg blowup avoided). H1 loads issued before barrier 1, drain under
// MFMA-H0. Last K-step split: Or stores issue before final Oi MFMAs.
// Swizzle slot = chunk ^ ((row>>1)&7). 256 blocks x 512 thr, LDS 96 KB.

constexpr int B = 32, S = 128, N = 256;

typedef _Float16 f16x8  __attribute__((ext_vector_type(8)));
typedef float    f32x16 __attribute__((ext_vector_type(16)));

union F16x8 { f16x8 v; __half2 h2[4]; };

#define MFMA32(a, bv, c) __builtin_amdgcn_mfma_f32_32x32x16_f16((a), (bv), (c), 0, 0, 0)

// LDS-only barrier: waits this thread's ds ops, NOT vmem (loads/stores fly).
#define LBAR() {                                                             \
        __builtin_amdgcn_sched_barrier(0);                                   \
        asm volatile("s_waitcnt lgkmcnt(0)" ::: "memory");                   \
        __builtin_amdgcn_s_barrier();                                        \
        __builtin_amdgcn_sched_barrier(0); }

__global__ __launch_bounds__(512, 2) void ComplexMixture_71313636983193_kernel(
    const float* __restrict__ R, const float* __restrict__ I,
    const float* __restrict__ W, float* __restrict__ Or, float* __restrict__ Oi)
{
    // AW[arr][n][.]: weighted A rows (n-half nh); Bt[arr][m][.]: B rows (mj).
    // row x, logical chunk c (8 s) at slot c ^ ((x>>1)&7).
    __shared__ alignas(16) _Float16 AW[2][128][128];  // 64 KB
    __shared__ alignas(16) _Float16 Bt[2][64][128];   // 32 KB

    const int pb   = blockIdx.x;
    const int lbid = (pb & 7) * 32 + (pb >> 3);   // 4 batches per XCD
    const int b   = lbid >> 3;
    const int rem = lbid & 7;
    const int nh  = rem >> 2;          // n-half (A rows 128)
    const int mj  = rem & 3;           // m-chunk (B rows 64)

    const int t  = threadIdx.x;
    const int wv = t >> 6, lane = t & 63;

    // staging tasks: A = arr(2) x nquad(32) x octet(8) -> all 512 threads;
    //                B = arr(2) x mquad(16) x octet(8) -> u < 128.
    const int arr   = t >> 8;          // 0 = real, 1 = imag (wave-uniform)
    const int u     = t & 255;
    const int nquad = u >> 3;          // 0..31
    const int octet = u & 7;           // s-octet within K-half
    const bool doB  = (u < 128);
    const int mquad = u >> 3;          // 0..15 when doB

    const size_t bb = (size_t)b * S * N;
    const float* arrp = arr ? I : R;
    const float* srcA = arrp + bb + nh * 128 + nquad * 4;
    const float* srcB = arrp + bb + mj * 64 + mquad * 4;
    const float* Wb   = W + b * S;

    // ---- issue H0 loads (s = octet*8 + 0..7) ----
    float4 fA[8], fB[8];
    #pragma unroll
    for (int s = 0; s < 8; ++s)
        fA[s] = *(const float4*)&srcA[(size_t)(octet * 8 + s) * N];
    if (doB) {
        #pragma unroll
        for (int s = 0; s < 8; ++s)
            fB[s] = *(const float4*)&srcB[(size_t)(octet * 8 + s) * N];
    }

    float w0[8], w1[8];
    {
        const float4 a0 = *(const float4*)&Wb[octet * 8];
        const float4 a1 = *(const float4*)&Wb[octet * 8 + 4];
        const float4 a2 = *(const float4*)&Wb[64 + octet * 8];
        const float4 a3 = *(const float4*)&Wb[64 + octet * 8 + 4];
        w0[0]=a0.x; w0[1]=a0.y; w0[2]=a0.z; w0[3]=a0.w;
        w0[4]=a1.x; w0[5]=a1.y; w0[6]=a1.z; w0[7]=a1.w;
        w1[0]=a2.x; w1[1]=a2.y; w1[2]=a2.z; w1[3]=a2.w;
        w1[4]=a3.x; w1[5]=a3.y; w1[6]=a3.z; w1[7]=a3.w;
    }

    // ---- cvt + write H0 (chunk c = octet) ----
    #pragma unroll
    for (int j = 0; j < 4; ++j) {
        const int n    = nquad * 4 + j;
        const int slot = octet ^ ((n >> 1) & 7);
        F16x8 fa;
        #pragma unroll
        for (int k = 0; k < 4; ++k)
            fa.h2[k] = __floats2half2_rn(((const float*)&fA[2*k])[j]   * w0[2*k],
                                         ((const float*)&fA[2*k+1])[j] * w0[2*k+1]);
        *(f16x8*)&AW[arr][n][slot * 8] = fa.v;
    }
    if (doB) {
        #pragma unroll
        for (int j = 0; j < 4; ++j) {
            const int m    = mquad * 4 + j;
            const int slot = octet ^ ((m >> 1) & 7);
            F16x8 fb;
            #pragma unroll
            for (int k = 0; k < 4; ++k)
                fb.h2[k] = __floats2half2_rn(((const float*)&fB[2*k])[j],
                                             ((const float*)&fB[2*k+1])[j]);
            *(f16x8*)&Bt[arr][m][slot * 8] = fb.v;
        }
    }

    // ---- issue H1 loads (s = 64 + ...); fly across the barrier ----
    float4 gA[8], gB[8];
    #pragma unroll
    for (int s = 0; s < 8; ++s)
        gA[s] = *(const float4*)&srcA[(size_t)(64 + octet * 8 + s) * N];
    if (doB) {
        #pragma unroll
        for (int s = 0; s < 8; ++s)
            gB[s] = *(const float4*)&srcB[(size_t)(64 + octet * 8 + s) * N];
    }

    LBAR();   // H0 tiles visible; H1 loads still in flight

    // ---- MFMA geometry: 4x2 grid of 32x32 wave-tiles ----
    const int sn = wv & 3;             // n sub-block 0..3
    const int sm = wv >> 2;            // m sub-block 0..1
    const int l31 = lane & 31, hi = lane >> 5;
    const int rowA = sn * 32 + l31;    const int sgA = (rowA >> 1) & 7;
    const int rowB = sm * 32 + l31;    const int sgB = (rowB >> 1) & 7;

    f32x16 dR = {0,0,0,0,0,0,0,0,0,0,0,0,0,0,0,0};
    f32x16 dA = {0,0,0,0,0,0,0,0,0,0,0,0,0,0,0,0};
    f32x16 dB = {0,0,0,0,0,0,0,0,0,0,0,0,0,0,0,0};

#define FRAG_STEP(ks) {                                                      \
        const int ca = ((2 * (ks) + hi) ^ sgA) * 8;                          \
        const int cb = ((2 * (ks) + hi) ^ sgB) * 8;                          \
        const f16x8 ar = *(const f16x8*)&AW[0][rowA][ca];                    \
        const f16x8 ai = *(const f16x8*)&AW[1][rowA][ca];                    \
        const f16x8 br = *(const f16x8*)&Bt[0][rowB][cb];                    \
        const f16x8 bi = *(const f16x8*)&Bt[1][rowB][cb];                    \
        dR = MFMA32(ar, br, dR); dR = MFMA32(ai, bi, dR);                    \
        dA = MFMA32(ai, br, dA); dB = MFMA32(ar, bi, dB); }

    // ---- MFMA over H0 (ks = 0..3) ----
    __builtin_amdgcn_s_setprio(1);
    FRAG_STEP(0); FRAG_STEP(1); FRAG_STEP(2); FRAG_STEP(3);
    __builtin_amdgcn_s_setprio(0);

    // ---- cvt + write H1 (chunk c = 8+octet; slots disjoint via bit 3) ----
    #pragma unroll
    for (int j = 0; j < 4; ++j) {
        const int n    = nquad * 4 + j;
        const int slot = (8 + octet) ^ ((n >> 1) & 7);
        F16x8 fa;
        #pragma unroll
        for (int k = 0; k < 4; ++k)
            fa.h2[k] = __floats2half2_rn(((const float*)&gA[2*k])[j]   * w1[2*k],
                                         ((const float*)&gA[2*k+1])[j] * w1[2*k+1]);
        *(f16x8*)&AW[arr][n][slot * 8] = fa.v;
    }
    if (doB) {
        #pragma unroll
        for (int j = 0; j < 4; ++j) {
            const int m    = mquad * 4 + j;
            const int slot = (8 + octet) ^ ((m >> 1) & 7);
            F16x8 fb;
            #pragma unroll
            for (int k = 0; k < 4; ++k)
                fb.h2[k] = __floats2half2_rn(((const float*)&gB[2*k])[j],
                                             ((const float*)&gB[2*k+1])[j]);
            *(f16x8*)&Bt[arr][m][slot * 8] = fb.v;
        }
    }

    LBAR();   // H1 tiles visible

    // ---- MFMA over H1 (ks = 4..7), last step split for early Or drain ----
    __builtin_amdgcn_s_setprio(1);
    FRAG_STEP(4); FRAG_STEP(5); FRAG_STEP(6);
    const int ca7 = ((2 * 7 + hi) ^ sgA) * 8;
    const int cb7 = ((2 * 7 + hi) ^ sgB) * 8;
    const f16x8 ar7 = *(const f16x8*)&AW[0][rowA][ca7];
    const f16x8 ai7 = *(const f16x8*)&AW[1][rowA][ca7];
    const f16x8 br7 = *(const f16x8*)&Bt[0][rowB][cb7];
    const f16x8 bi7 = *(const f16x8*)&Bt[1][rowB][cb7];
    dR = MFMA32(ar7, br7, dR); dR = MFMA32(ai7, bi7, dR);
    __builtin_amdgcn_s_setprio(0);

    // C/D layout (m74/m101, R13-verified): col = lane&31,
    // row = (r&3) + 8*(r>>2) + 4*hi.
    const int mm = mj * 64 + sm * 32 + l31;
    #pragma unroll
    for (int r = 0; r < 16; ++r) {
        const int nn = nh * 128 + sn * 32 + (r & 3) + 8 * (r >> 2) + 4 * hi;
        Or[((size_t)b * N + nn) * N + mm] = dR[r];   // drains under Oi MFMAs
    }

    __builtin_amdgcn_s_setprio(1);
    dA = MFMA32(ai7, br7, dA); dB = MFMA32(ar7, bi7, dB);
    __builtin_amdgcn_s_setprio(0);

    #pragma unroll
    for (int r = 0; r < 16; ++r) {
        const int nn = nh * 128 + sn * 32 + (r & 3) + 8 * (r >> 2) + 4 * hi;
        Oi[((size_t)b * N + nn) * N + mm] = dA[r] - dB[r];
    }
}

extern "C" void kernel_launch(void* const* d_in, const int* in_sizes, int n_in,
                              void* d_out, int out_size, void* d_ws, size_t ws_size,
                              hipStream_t stream) {
    const float* R = (const float*)d_in[0];
    const float* I = (const float*)d_in[1];
    const float* W = (const float*)d_in[2];
    float* Or = (float*)d_out;
    float* Oi = (float*)d_out + (size_t)B * N * N;

    ComplexMixture_71313636983193_kernel<<<dim3(256), dim3(512), 0, stream>>>(
        R, I, W, Or, Oi);
}

// Round 15
// 12.787 us; speedup vs baseline: 1.3071x; 1.3071x over previous
//
#include <hip/hip_runtime.h>
#include <hip/hip_fp16.h>

// ComplexMixture: B=32, S=128, N=256
// Or[b,n,m] = sum_s w[b,s]*(r[b,s,n]*r[b,s,m] + i[b,s,n]*i[b,s,m])
// Oi[b,n,m] = sum_s w[b,s]*(i[b,s,n]*r[b,s,m] - r[b,s,n]*i[b,s,m])
//
// R15 = R12 (proven 12.62 µs) + A-fragment register caching across tiles:
// tile-1 and tile-2 share the A operand; caching awrk/awik[4] (32 VGPR,
// statically indexed) removes tile-2's 8 A-frag ds_read_b128 per thread
// (~17% of fragment traffic) and shortens tile-2's LDS critical path.
// Everything else identical to R12: counted lgkm-only barriers (B2 loads
// and tile-1 stores stay in flight across barriers), K-full staging,
// swizzle slot = chunk ^ ((row>>1)&7), ms-split tail, 256 x 512, 96 KB LDS.

constexpr int B = 32, S = 128, N = 256;

typedef _Float16 f16x8 __attribute__((ext_vector_type(8)));
typedef float    f32x4 __attribute__((ext_vector_type(4)));

union F16x8 { f16x8 v; __half2 h2[4]; };

#define MFMA16(a, bv, c) __builtin_amdgcn_mfma_f32_16x16x32_f16((a), (bv), (c), 0, 0, 0)

// LDS-only barrier: waits this thread's ds ops, NOT vmem (loads/stores fly).
#define LBAR() {                                                             \
        __builtin_amdgcn_sched_barrier(0);                                   \
        asm volatile("s_waitcnt lgkmcnt(0)" ::: "memory");                   \
        __builtin_amdgcn_s_barrier();                                        \
        __builtin_amdgcn_sched_barrier(0); }

__global__ __launch_bounds__(512, 2) void ComplexMixture_71313636983193_kernel(
    const float* __restrict__ R, const float* __restrict__ I,
    const float* __restrict__ W, float* __restrict__ Or, float* __restrict__ Oi)
{
    // T[0..1] = w*r, w*i (A rows = n-chunk ti)
    // T[2..3] = r, i (B rows = m-chunk tj1);  T[4..5] = r, i (m-chunk tj2)
    // row x, logical chunk c (8 s) at slot c ^ ((x>>1)&7)
    __shared__ alignas(16) _Float16 T[6][64][128];   // 96 KB

    const int pb   = blockIdx.x;
    const int lbid = (pb & 7) * 32 + (pb >> 3);   // 4 batches per XCD
    const int b   = lbid >> 3;
    const int rem = lbid & 7;
    const int ti  = rem >> 1;          // A-side n-chunk
    const int uu  = rem & 1;
    const int tj1 = uu * 2, tj2 = uu * 2 + 1;   // the two B-side m-chunks

    const int t  = threadIdx.x;
    const int wv = t >> 6, lane = t & 63;

    // staging task: 512 = nquad(16) x octet(16) x arr(2)
    const int nquad = t & 15;          // n = nquad*4 + j
    const int octet = (t >> 4) & 15;   // s-octet 0..15 (full K)
    const int arr   = t >> 8;          // 0 = real, 1 = imag (wave-uniform)
    const int s0    = octet * 8;

    const size_t bb = (size_t)b * S * N;
    const float* base  = (arr ? I : R) + bb + nquad * 4;
    const float* srcA  = base + ti  * 64;
    const float* srcB1 = base + tj1 * 64;
    const float* srcB2 = base + tj2 * 64;
    const float* Wb = W + b * S;

    // ---- issue A + B1 loads (8 rows of 4 n each) ----
    float4 fA[8], fB1[8];
    #pragma unroll
    for (int s = 0; s < 8; ++s)
        fA[s] = *(const float4*)&srcA[(size_t)(s0 + s) * N];
    #pragma unroll
    for (int s = 0; s < 8; ++s)
        fB1[s] = *(const float4*)&srcB1[(size_t)(s0 + s) * N];

    float w8[8];
    {
        const float4 a0 = *(const float4*)&Wb[s0];
        const float4 a1 = *(const float4*)&Wb[s0 + 4];
        w8[0]=a0.x; w8[1]=a0.y; w8[2]=a0.z; w8[3]=a0.w;
        w8[4]=a1.x; w8[5]=a1.y; w8[6]=a1.z; w8[7]=a1.w;
    }

    // ---- cvt + write A (weighted) and B1 ----
    #pragma unroll
    for (int j = 0; j < 4; ++j) {
        const int n    = nquad * 4 + j;
        const int slot = octet ^ ((n >> 1) & 7);
        F16x8 fa, fb;
        #pragma unroll
        for (int k = 0; k < 4; ++k) {
            fa.h2[k] = __floats2half2_rn(((const float*)&fA[2*k])[j]   * w8[2*k],
                                         ((const float*)&fA[2*k+1])[j] * w8[2*k+1]);
            fb.h2[k] = __floats2half2_rn(((const float*)&fB1[2*k])[j],
                                         ((const float*)&fB1[2*k+1])[j]);
        }
        *(f16x8*)&T[arr][n][slot * 8]     = fa.v;
        *(f16x8*)&T[2 + arr][n][slot * 8] = fb.v;
    }

    // ---- issue B2 loads; they fly across the (lgkm-only) barrier ----
    float4 fB2[8];
    #pragma unroll
    for (int s = 0; s < 8; ++s)
        fB2[s] = *(const float4*)&srcB2[(size_t)(s0 + s) * N];

    LBAR();   // A, B1 visible; B2 loads still in flight

    // ---- MFMA geometry (R9-proven): wave = 16(n) x 32(m) sub-tile ----
    const int wn = (wv & 3) * 16;
    const int wm = (wv >> 2) * 32;
    const int fr16 = lane & 15, kb = lane >> 4;
    const int ra  = wn + fr16;          const int sa  = (ra  >> 1) & 7;
    const int rb0 = wm + fr16;          const int sb0 = (rb0 >> 1) & 7;
    const int rb1 = wm + 16 + fr16;     const int sb1 = (rb1 >> 1) & 7;

    // A fragments cached in registers across BOTH tiles (static indices).
    f16x8 awrk[4], awik[4];

#define CACHE_A(ks) { const int ca = (((ks) * 4 + kb) ^ sa) * 8;             \
        awrk[ks] = *(const f16x8*)&T[0][ra][ca];                             \
        awik[ks] = *(const f16x8*)&T[1][ra][ca]; }
#define STEP_B(TB, ks, ms, aR, aA, aB) { const int K = (ks) * 4 + kb;        \
        const int rb = (ms) ? rb1 : rb0;                                     \
        const int cb = (K ^ ((ms) ? sb1 : sb0)) * 8;                         \
        const f16x8 br = *(const f16x8*)&T[TB][rb][cb];                      \
        const f16x8 bi = *(const f16x8*)&T[(TB) + 1][rb][cb];                \
        aR[ms] = MFMA16(awrk[ks], br, aR[ms]);                               \
        aR[ms] = MFMA16(awik[ks], bi, aR[ms]);                               \
        aA[ms] = MFMA16(awik[ks], br, aA[ms]);                               \
        aB[ms] = MFMA16(awrk[ks], bi, aB[ms]); }

    const int n0 = ti * 64;
    const int nn = n0 + wn + kb * 4;

#define STORE_MS(TJ, ms, aR, aA, aB) {                                       \
        const int mm = (TJ) * 64 + wm + (ms) * 16 + fr16;                    \
        _Pragma("unroll")                                                    \
        for (int r = 0; r < 4; ++r) {                                        \
            const size_t o = ((size_t)b * N + nn + r) * N + mm;              \
            Or[o] = aR[ms][r];                                               \
            Oi[o] = aA[ms][r] - aB[ms][r];                                   \
        } }

#define B2CVT(j) {                                                           \
        const int n    = nquad * 4 + (j);                                    \
        const int slot = octet ^ ((n >> 1) & 7);                             \
        F16x8 fb;                                                            \
        _Pragma("unroll")                                                    \
        for (int k = 0; k < 4; ++k)                                          \
            fb.h2[k] = __floats2half2_rn(((const float*)&fB2[2*k])[(j)],     \
                                         ((const float*)&fB2[2*k+1])[(j)]);  \
        *(f16x8*)&T[4 + arr][n][slot * 8] = fb.v; }

    // ---- tile 1: full-K MFMA (B2 loads draining underneath) ----
    f32x4 a1R[2] = {}, a1A[2] = {}, a1B[2] = {};
    __builtin_amdgcn_s_setprio(1);
    CACHE_A(0); STEP_B(2, 0, 0, a1R, a1A, a1B); STEP_B(2, 0, 1, a1R, a1A, a1B);
    CACHE_A(1); STEP_B(2, 1, 0, a1R, a1A, a1B); STEP_B(2, 1, 1, a1R, a1A, a1B);
    CACHE_A(2); STEP_B(2, 2, 0, a1R, a1A, a1B); STEP_B(2, 2, 1, a1R, a1A, a1B);
    CACHE_A(3); STEP_B(2, 3, 0, a1R, a1A, a1B); STEP_B(2, 3, 1, a1R, a1A, a1B);
    __builtin_amdgcn_s_setprio(0);

    // ---- tile1 stores interleaved with B2 cvt+write ----
    STORE_MS(tj1, 0, a1R, a1A, a1B);
    B2CVT(0); B2CVT(1);
    STORE_MS(tj1, 1, a1R, a1A, a1B);
    B2CVT(2); B2CVT(3);

    LBAR();   // B2 visible; tile1 stores still in flight

    // ---- tile 2: A frags from registers (no LDS A reads), ms-split tail --
    f32x4 a2R[2] = {}, a2A[2] = {}, a2B[2] = {};
    __builtin_amdgcn_s_setprio(1);
    STEP_B(4, 0, 0, a2R, a2A, a2B); STEP_B(4, 0, 1, a2R, a2A, a2B);
    STEP_B(4, 1, 0, a2R, a2A, a2B); STEP_B(4, 1, 1, a2R, a2A, a2B);
    STEP_B(4, 2, 0, a2R, a2A, a2B); STEP_B(4, 2, 1, a2R, a2A, a2B);
    STEP_B(4, 3, 0, a2R, a2A, a2B);
    __builtin_amdgcn_s_setprio(0);
    STORE_MS(tj2, 0, a2R, a2A, a2B);   // drain starts while ms=1 finishes
    __builtin_amdgcn_s_setprio(1);
    STEP_B(4, 3, 1, a2R, a2A, a2B);
    __builtin_amdgcn_s_setprio(0);
    STORE_MS(tj2, 1, a2R, a2A, a2B);
}

extern "C" void kernel_launch(void* const* d_in, const int* in_sizes, int n_in,
                              void* d_out, int out_size, void* d_ws, size_t ws_size,
                              hipStream_t stream) {
    const float* R = (const float*)d_in[0];
    const float* I = (const float*)d_in[1];
    const float* W = (const float*)d_in[2];
    float* Or = (float*)d_out;
    float* Oi = (float*)d_out + (size_t)B * N * N;

    ComplexMixture_71313636983193_kernel<<<dim3(256), dim3(512), 0, stream>>>(
        R, I, W, Or, Oi);
}